// Round 8
// baseline (106.464 us; speedup 1.0000x reference)
//
#include <hip/hip_runtime.h>
#include <hip/hip_cooperative_groups.h>

namespace cg = cooperative_groups;

#define EPSV 1e-8f
#define CENTER_VAR 0.1f
#define SIZE_VAR 0.2f
#define TPB 256
#define MAXA 2048   // LDS infer-list capacity (== P here)

__device__ __forceinline__ float4 decode_box(float4 loc, float4 pr) {
    float cx = pr.x + loc.x * CENTER_VAR * pr.z;
    float cy = pr.y + loc.y * CENTER_VAR * pr.w;
    float w  = pr.z * __expf(loc.z * SIZE_VAR);
    float h  = pr.w * __expf(loc.w * SIZE_VAR);
    float x0 = cx - w * 0.5f;
    float y0 = cy - h * 0.5f;
    return make_float4(x0, y0, x0 + w, y0 + h);
}

__device__ __forceinline__ float giou_pair(float4 A, float4 Bx) {
    float ix = fminf(A.z, Bx.z) - fmaxf(A.x, Bx.x);
    float iy = fminf(A.w, Bx.w) - fmaxf(A.y, Bx.y);
    float inter = fmaxf(ix, 0.f) * fmaxf(iy, 0.f);
    float area_a = (A.z - A.x) * (A.w - A.y);
    float area_b = (Bx.z - Bx.x) * (Bx.w - Bx.y);
    float uni = area_a + area_b - inter;
    float iou = __fdividef(inter, fmaxf(uni, EPSV));
    float ex = fmaxf(A.z, Bx.z) - fminf(A.x, Bx.x);
    float ey = fmaxf(A.w, Bx.w) - fminf(A.y, Bx.y);
    float enc = ex * ey;
    return iou - __fdividef(enc - uni, fmaxf(enc, EPSV));
}

// Single cooperative kernel. Block blk = b*bpb + sub covers priors
// [sub*TPB, sub*TPB+TPB) of batch b. All per-block output slots are written
// unconditionally -> no workspace zero-init needed, no global atomics.
__global__ __launch_bounds__(TPB) void fused_coop(
    const float* __restrict__ conf,
    const float* __restrict__ loc,
    const int*   __restrict__ tconf,
    const float* __restrict__ tloc,
    const float* __restrict__ priors,
    int B, int P, int C, int bpb,
    int*    __restrict__ cnt_a,    // [nblk] per-block infer count
    int*    __restrict__ cnt_t,    // [nblk] per-block target count
    float*  __restrict__ s_part,   // [nblk] per-block giou partial
    float4* __restrict__ regions,  // [nblk][TPB] per-block infer boxes
    float*  __restrict__ out) {
    cg::grid_group grid = cg::this_grid();

    int blk = blockIdx.x;
    int b   = blk / bpb;
    int sub = blk - b * bpb;
    int p   = sub * TPB + threadIdx.x;
    size_t idx = (size_t)b * P + p;
    bool live = p < P;
    int lane = threadIdx.x & 63, wid = threadIdx.x >> 6;

    __shared__ int   na_sh;
    __shared__ int   wcnt[TPB / 64];
    __shared__ float wsum[TPB / 64];
    __shared__ float4 ab[MAXA];

    if (threadIdx.x == 0) na_sh = 0;
    __syncthreads();

    // ---------------- Phase 1: masks + per-block compaction ----------------
    bool pos_t = live && (tconf[idx] > 0);
    unsigned long long bm = __ballot(pos_t);
    if (lane == 0) wcnt[wid] = __popcll(bm);

    if (pos_t) {
        // pos_infer: max_p > 0.5 <=> sum(exp(l - max)) < 2 ; argmax > 0
        const float* cf = conf + idx * C;
        float m; int mi; float se;
        if (C == 21) {
            float v[21];
            #pragma unroll
            for (int c = 0; c < 21; ++c) v[c] = cf[c];
            m = v[0]; mi = 0;
            #pragma unroll
            for (int c = 1; c < 21; ++c) { if (v[c] > m) { m = v[c]; mi = c; } }
            se = 0.f;
            #pragma unroll
            for (int c = 0; c < 21; ++c) se += __expf(v[c] - m);
        } else {
            m = cf[0]; mi = 0;
            for (int c = 1; c < C; ++c) { float v = cf[c]; if (v > m) { m = v; mi = c; } }
            se = 0.f;
            for (int c = 0; c < C; ++c) se += __expf(cf[c] - m);
        }
        if (se < 2.0f && mi > 0) {
            float4 l  = ((const float4*)loc)[idx];
            float4 pr = ((const float4*)priors)[p];
            int k = atomicAdd(&na_sh, 1);                  // LDS atomic
            regions[(size_t)blk * TPB + k] = decode_box(l, pr);
        }
    }
    __syncthreads();
    if (threadIdx.x == 0) {
        int c = 0;
        #pragma unroll
        for (int w = 0; w < TPB / 64; ++w) c += wcnt[w];
        cnt_t[blk] = c;        // unconditional slot writes
        cnt_a[blk] = na_sh;
    }

    grid.sync();

    // -------- Phase 2: stage batch infer list to LDS, pair sums ----------
    int nA = 0;
    for (int r = 0; r < bpb; ++r) {
        int c = cnt_a[b * bpb + r];
        int take = min(c, MAXA - nA);
        for (int i = threadIdx.x; i < take; i += TPB)
            ab[nA + i] = regions[(size_t)(b * bpb + r) * TPB + i];
        nA += take;
    }
    __syncthreads();

    float acc = 0.f;
    if (pos_t && nA > 0) {
        float4 l  = ((const float4*)tloc)[idx];
        float4 pr = ((const float4*)priors)[p];
        float4 T = decode_box(l, pr);
        for (int i = 0; i < nA; ++i) acc += giou_pair(ab[i], T);
    }
    for (int off = 32; off > 0; off >>= 1) acc += __shfl_down(acc, off);
    if (lane == 0) wsum[wid] = acc;
    __syncthreads();
    if (threadIdx.x == 0) {
        float t = 0.f;
        #pragma unroll
        for (int w = 0; w < TPB / 64; ++w) t += wsum[w];
        s_part[blk] = t;       // unconditional slot write
    }

    grid.sync();

    // ---------------- Phase 3: finalize on block 0 ----------------
    if (blk == 0) {
        __shared__ float tterm[TPB];
        __shared__ float tnt[TPB];
        float term = 0.f, ntf = 0.f;
        if (threadIdx.x < B) {
            int bb = threadIdx.x;
            int nt = 0, na = 0; float s = 0.f;
            for (int r = 0; r < bpb; ++r) {
                nt += cnt_t[bb * bpb + r];
                na += cnt_a[bb * bpb + r];
                s  += s_part[bb * bpb + r];
            }
            ntf = (float)nt;
            bool bt = nt > 0, ba = na > 0;
            term = (bt && ba) ? (ntf - s / fmaxf(ntf, 1.f))
                              : ((bt != ba) ? 1.f : 0.f);
        }
        tterm[threadIdx.x] = term;
        tnt[threadIdx.x]   = ntf;
        __syncthreads();
        if (threadIdx.x == 0) {
            float tsum = 0.f, nsum = 0.f;
            for (int bb = 0; bb < B; ++bb) { tsum += tterm[bb]; nsum += tnt[bb]; }
            out[0] = tsum / fmaxf(nsum, 1.f);
        }
    }
}

extern "C" void kernel_launch(void* const* d_in, const int* in_sizes, int n_in,
                              void* d_out, int out_size, void* d_ws, size_t ws_size,
                              hipStream_t stream) {
    const float* conf   = (const float*)d_in[0];
    const float* loc    = (const float*)d_in[1];
    const int*   tconf  = (const int*)  d_in[2];
    const float* tloc   = (const float*)d_in[3];
    const float* priors = (const float*)d_in[4];
    float* out = (float*)d_out;

    int P = in_sizes[4] / 4;          // priors: [P,4]
    int B = in_sizes[2] / P;          // target_confidence: [B,P]
    int C = in_sizes[0] / (B * P);    // confidence: [B,P,C]
    int bpb  = (P + TPB - 1) / TPB;   // blocks per batch (8)
    int nblk = B * bpb;               // 64

    // ws layout (no init required — every slot written unconditionally):
    // cnt_a[nblk] | cnt_t[nblk] | s_part[nblk] | regions[nblk][TPB] float4
    int*   cnt_a  = (int*)d_ws;
    int*   cnt_t  = cnt_a + nblk;
    float* s_part = (float*)(cnt_t + nblk);
    size_t hdr = ((size_t)nblk * 3 * sizeof(int) + 15) & ~(size_t)15;
    float4* regions = (float4*)((char*)d_ws + hdr);

    void* args[] = { (void*)&conf, (void*)&loc, (void*)&tconf, (void*)&tloc,
                     (void*)&priors, (void*)&B, (void*)&P, (void*)&C, (void*)&bpb,
                     (void*)&cnt_a, (void*)&cnt_t, (void*)&s_part,
                     (void*)&regions, (void*)&out };
    hipLaunchCooperativeKernel((void*)fused_coop, dim3(nblk), dim3(TPB),
                               args, 0, stream);
}

// Round 9
// 83.820 us; speedup vs baseline: 1.2702x; 1.2702x over previous
//
#include <hip/hip_runtime.h>

#define EPSV 1e-8f
#define CENTER_VAR 0.1f
#define SIZE_VAR 0.2f
#define WSZ 64      // block = one wave
#define MAXA 2048   // LDS infer-list capacity (== P)

__device__ __forceinline__ float4 decode_box(float4 loc, float4 pr) {
    float cx = pr.x + loc.x * CENTER_VAR * pr.z;
    float cy = pr.y + loc.y * CENTER_VAR * pr.w;
    float w  = pr.z * __expf(loc.z * SIZE_VAR);
    float h  = pr.w * __expf(loc.w * SIZE_VAR);
    float x0 = cx - w * 0.5f;
    float y0 = cy - h * 0.5f;
    return make_float4(x0, y0, x0 + w, y0 + h);
}

__device__ __forceinline__ float giou_pair(float4 A, float4 Bx) {
    float ix = fminf(A.z, Bx.z) - fmaxf(A.x, Bx.x);
    float iy = fminf(A.w, Bx.w) - fmaxf(A.y, Bx.y);
    float inter = fmaxf(ix, 0.f) * fmaxf(iy, 0.f);
    float area_a = (A.z - A.x) * (A.w - A.y);
    float area_b = (Bx.z - Bx.x) * (Bx.w - Bx.y);
    float uni = area_a + area_b - inter;
    float iou = __fdividef(inter, fmaxf(uni, EPSV));
    float ex = fmaxf(A.z, Bx.z) - fminf(A.x, Bx.x);
    float ey = fmaxf(A.w, Bx.w) - fminf(A.y, Bx.y);
    float enc = ex * ey;
    return iou - __fdividef(enc - uni, fmaxf(enc, EPSV));
}

// k1: one wave per 64 priors. Ballot-prefix compaction, zero atomics,
// zero barriers, all output slots written unconditionally.
__global__ __launch_bounds__(WSZ) void mask_kernel(
    const float* __restrict__ conf,
    const float* __restrict__ loc,
    const int*   __restrict__ tconf,
    const float* __restrict__ priors,
    int P, int C, int bpb,
    int* __restrict__ done,
    int* __restrict__ cnt_a, int* __restrict__ cnt_t,
    float4* __restrict__ regions) {
    int blk = blockIdx.x;
    int lane = threadIdx.x;
    int b = blk / bpb;
    int p = (blk - b * bpb) * WSZ + lane;
    size_t idx = (size_t)b * P + p;
    bool live = p < P;

    if (blk == 0 && lane == 0) *done = 0;   // k2 (stream-ordered) reads this

    bool pos_t = live && (tconf[idx] > 0);
    unsigned long long bm_t = __ballot(pos_t);

    bool inf = false;
    float4 box = make_float4(0.f, 0.f, 0.f, 0.f);
    if (pos_t) {
        // pos_infer: max_p > 0.5 <=> sum(exp(l - max)) < 2 ; argmax > 0
        const float* cf = conf + idx * C;
        float m; int mi; float se;
        if (C == 21) {
            float v[21];
            #pragma unroll
            for (int c = 0; c < 21; ++c) v[c] = cf[c];
            m = v[0]; mi = 0;
            #pragma unroll
            for (int c = 1; c < 21; ++c) { if (v[c] > m) { m = v[c]; mi = c; } }
            se = 0.f;
            #pragma unroll
            for (int c = 0; c < 21; ++c) se += __expf(v[c] - m);
        } else {
            m = cf[0]; mi = 0;
            for (int c = 1; c < C; ++c) { float v = cf[c]; if (v > m) { m = v; mi = c; } }
            se = 0.f;
            for (int c = 0; c < C; ++c) se += __expf(cf[c] - m);
        }
        if (se < 2.0f && mi > 0) {
            float4 l  = ((const float4*)loc)[idx];
            float4 pr = ((const float4*)priors)[p];
            box = decode_box(l, pr);
            inf = true;
        }
    }
    unsigned long long bm_i = __ballot(inf);
    if (inf) {
        int k = __popcll(bm_i & ((1ull << lane) - 1ull));   // ballot-prefix slot
        regions[(size_t)blk * WSZ + k] = box;
    }
    if (lane == 0) {
        cnt_t[blk] = __popcll(bm_t);    // unconditional slot writes
        cnt_a[blk] = __popcll(bm_i);
    }
}

// k2: one wave per 64 targets; batch infer list staged to LDS; per-block
// partial written unconditionally; last-done block finalizes inline.
__global__ __launch_bounds__(WSZ) void pair_kernel(
    const int*   __restrict__ tconf,
    const float* __restrict__ tloc,
    const float* __restrict__ priors,
    const float4* __restrict__ regions,
    const int* __restrict__ cnt_a, const int* __restrict__ cnt_t,
    int* __restrict__ done,
    float* __restrict__ s_part,
    int B, int P, int bpb, int nblk,
    float* __restrict__ out) {
    int blk = blockIdx.x;
    int lane = threadIdx.x;
    int b = blk / bpb;
    int base = b * bpb;
    int p = (blk - base) * WSZ + lane;
    size_t idx = (size_t)b * P + p;
    bool live = p < P;

    __shared__ float4 ab[MAXA];
    __shared__ int cnts[64];          // bpb <= 64 assumed (== 32 here)

    // parallel count prefetch (breaks serial L2 chain)
    cnts[lane] = (lane < bpb) ? cnt_a[base + lane] : 0;
    __syncthreads();
    int nA = 0;
    for (int r = 0; r < bpb; ++r) {   // redundant per-lane prefix from LDS
        int c = cnts[r];
        for (int i = lane; i < c; i += WSZ)
            ab[nA + i] = regions[(size_t)(base + r) * WSZ + i];
        nA += c;
    }
    __syncthreads();

    bool pos_t = live && (tconf[idx] > 0);
    float acc = 0.f;
    if (pos_t && nA > 0) {
        float4 l  = ((const float4*)tloc)[idx];
        float4 pr = ((const float4*)priors)[p];
        float4 T = decode_box(l, pr);
        for (int i = 0; i < nA; ++i) acc += giou_pair(ab[i], T);
    }
    for (int off = 32; off > 0; off >>= 1) acc += __shfl_down(acc, off);
    if (lane == 0) s_part[blk] = acc;     // unconditional slot write
    __threadfence();                      // device-scope release of s_part

    int last = 0;
    if (lane == 0) {
        int old = __hip_atomic_fetch_add(done, 1, __ATOMIC_ACQ_REL,
                                         __HIP_MEMORY_SCOPE_AGENT);
        last = (old == nblk - 1);
    }
    last = __shfl(last, 0);
    if (!last) return;

    // ---- finalize (64 lanes) ----
    __shared__ float sb[16];
    __shared__ int   ntb[16], nab[16];
    if (lane < 16) { sb[lane] = 0.f; ntb[lane] = 0; nab[lane] = 0; }
    __syncthreads();
    for (int slot = lane; slot < nblk; slot += WSZ) {
        int bb = slot / bpb;
        float sv = __hip_atomic_load(&s_part[slot], __ATOMIC_RELAXED,
                                     __HIP_MEMORY_SCOPE_AGENT);
        atomicAdd(&sb[bb], sv);
        atomicAdd(&ntb[bb], cnt_t[slot]);   // written by k1 (kernel boundary)
        atomicAdd(&nab[bb], cnt_a[slot]);
    }
    __syncthreads();
    if (lane == 0) {
        float tsum = 0.f, nsum = 0.f;
        for (int bb = 0; bb < B; ++bb) {
            float ntf = (float)ntb[bb];
            bool bt = ntb[bb] > 0, ba = nab[bb] > 0;
            float term = (bt && ba) ? (ntf - sb[bb] / fmaxf(ntf, 1.f))
                                    : ((bt != ba) ? 1.f : 0.f);
            tsum += term;
            nsum += ntf;
        }
        out[0] = tsum / fmaxf(nsum, 1.f);
    }
}

extern "C" void kernel_launch(void* const* d_in, const int* in_sizes, int n_in,
                              void* d_out, int out_size, void* d_ws, size_t ws_size,
                              hipStream_t stream) {
    const float* conf   = (const float*)d_in[0];
    const float* loc    = (const float*)d_in[1];
    const int*   tconf  = (const int*)  d_in[2];
    const float* tloc   = (const float*)d_in[3];
    const float* priors = (const float*)d_in[4];
    float* out = (float*)d_out;

    int P = in_sizes[4] / 4;          // priors: [P,4]
    int B = in_sizes[2] / P;          // target_confidence: [B,P]
    int C = in_sizes[0] / (B * P);    // confidence: [B,P,C]
    int bpb  = (P + WSZ - 1) / WSZ;   // waves per batch (32)
    int nblk = B * bpb;               // 256

    // ws: done[4 ints pad] | cnt_a[nblk] | cnt_t[nblk] | s_part[nblk] | regions
    int*   done   = (int*)d_ws;
    int*   cnt_a  = done + 4;
    int*   cnt_t  = cnt_a + nblk;
    float* s_part = (float*)(cnt_t + nblk);
    size_t hdr = (16 + (size_t)nblk * 3 * sizeof(int) + 15) & ~(size_t)15;
    float4* regions = (float4*)((char*)d_ws + hdr);

    mask_kernel<<<nblk, WSZ, 0, stream>>>(conf, loc, tconf, priors,
                                          P, C, bpb, done, cnt_a, cnt_t, regions);
    pair_kernel<<<nblk, WSZ, 0, stream>>>(tconf, tloc, priors, regions,
                                          cnt_a, cnt_t, done, s_part,
                                          B, P, bpb, nblk, out);
}

// Round 10
// 72.939 us; speedup vs baseline: 1.4596x; 1.1492x over previous
//
#include <hip/hip_runtime.h>

#define EPSV 1e-8f
#define CENTER_VAR 0.1f
#define SIZE_VAR 0.2f
#define TPB 256
#define MAXA 2048   // LDS infer-list capacity (== P)

__device__ __forceinline__ float4 decode_box(float4 loc, float4 pr) {
    float cx = pr.x + loc.x * CENTER_VAR * pr.z;
    float cy = pr.y + loc.y * CENTER_VAR * pr.w;
    float w  = pr.z * __expf(loc.z * SIZE_VAR);
    float h  = pr.w * __expf(loc.w * SIZE_VAR);
    float x0 = cx - w * 0.5f;
    float y0 = cy - h * 0.5f;
    return make_float4(x0, y0, x0 + w, y0 + h);
}

__device__ __forceinline__ float giou_pair(float4 A, float4 Bx) {
    float ix = fminf(A.z, Bx.z) - fmaxf(A.x, Bx.x);
    float iy = fminf(A.w, Bx.w) - fmaxf(A.y, Bx.y);
    float inter = fmaxf(ix, 0.f) * fmaxf(iy, 0.f);
    float area_a = (A.z - A.x) * (A.w - A.y);
    float area_b = (Bx.z - Bx.x) * (Bx.w - Bx.y);
    float uni = area_a + area_b - inter;
    float iou = __fdividef(inter, fmaxf(uni, EPSV));
    float ex = fmaxf(A.z, Bx.z) - fminf(A.x, Bx.x);
    float ey = fmaxf(A.w, Bx.w) - fminf(A.y, Bx.y);
    float enc = ex * ey;
    return iou - __fdividef(enc - uni, fmaxf(enc, EPSV));
}

// k1: 64 blocks x 256. Per-wave ballot slots; zero atomics, zero init needed.
// Requires P % 256 == 0 (holds: P=2048).
__global__ __launch_bounds__(TPB) void mask_kernel(
    const float* __restrict__ conf,
    const float* __restrict__ loc,
    const int*   __restrict__ tconf,
    const float* __restrict__ priors,
    int P, int C,
    int* __restrict__ cnt_a,                 // [nwave] per-wave infer count
    unsigned long long* __restrict__ masks,  // [nwave] pos_target bitmask
    float4* __restrict__ regions) {          // [nwave][64] compacted boxes
    int g = blockIdx.x * TPB + threadIdx.x;
    int lane = threadIdx.x & 63;
    int b = g / P;
    int p = g - b * P;
    int ws = g >> 6;                         // global wave slot

    bool pos_t = tconf[g] > 0;
    unsigned long long bm_t = __ballot(pos_t);

    bool inf = false;
    float4 box;
    if (pos_t) {
        // pos_infer: max_p > 0.5 <=> sum(exp(l - max)) < 2 ; argmax > 0
        const float* cf = conf + (size_t)g * C;
        float m; int mi; float se;
        if (C == 21) {
            float v[21];
            #pragma unroll
            for (int c = 0; c < 21; ++c) v[c] = cf[c];
            m = v[0]; mi = 0;
            #pragma unroll
            for (int c = 1; c < 21; ++c) { if (v[c] > m) { m = v[c]; mi = c; } }
            se = 0.f;
            #pragma unroll
            for (int c = 0; c < 21; ++c) se += __expf(v[c] - m);
        } else {
            m = cf[0]; mi = 0;
            for (int c = 1; c < C; ++c) { float v = cf[c]; if (v > m) { m = v; mi = c; } }
            se = 0.f;
            for (int c = 0; c < C; ++c) se += __expf(cf[c] - m);
        }
        if (se < 2.0f && mi > 0) {
            float4 l  = ((const float4*)loc)[g];
            float4 pr = ((const float4*)priors)[p];
            box = decode_box(l, pr);
            inf = true;
        }
    }
    unsigned long long bm_i = __ballot(inf);
    if (inf) {
        int k = __popcll(bm_i & ((1ull << lane) - 1ull));   // ballot-prefix
        regions[((size_t)ws << 6) + k] = box;
    }
    if (lane == 0) {
        masks[ws] = bm_t;                    // unconditional slot writes
        cnt_a[ws] = __popcll(bm_i);
    }
}

// k2: 64 blocks x 256. Batch infer list staged to LDS; per-block partial
// written unconditionally. No fences, no atomics.
__global__ __launch_bounds__(TPB) void pair_kernel(
    const float* __restrict__ tloc,
    const float* __restrict__ priors,
    const float4* __restrict__ regions,
    const int* __restrict__ cnt_a,
    const unsigned long long* __restrict__ masks,
    float* __restrict__ s_part,              // [nblk]
    int P) {
    int blk = blockIdx.x;
    int g = blk * TPB + threadIdx.x;
    int lane = threadIdx.x & 63, wid = threadIdx.x >> 6;
    int b = g / P;
    int p = g - b * P;
    int ws = g >> 6;
    int wpb = P >> 6;                        // wave slots per batch (32)
    int base_ws = b * wpb;

    __shared__ float4 ab[MAXA];
    __shared__ int cnts[64];
    __shared__ float wsum[TPB / 64];

    // parallel count prefetch (breaks serial L2 chain)
    for (int i = threadIdx.x; i < wpb; i += TPB) cnts[i] = cnt_a[base_ws + i];
    __syncthreads();
    int nA = 0;
    for (int r = 0; r < wpb; ++r) {
        int c = cnts[r];
        for (int i = threadIdx.x; i < c; i += TPB)
            ab[nA + i] = regions[((size_t)(base_ws + r) << 6) + i];
        nA += c;
    }
    __syncthreads();

    unsigned long long bm = masks[ws];       // broadcast load per wave
    bool pos_t = (bm >> lane) & 1ull;
    float acc = 0.f;
    if (pos_t && nA > 0) {
        float4 l  = ((const float4*)tloc)[g];
        float4 pr = ((const float4*)priors)[p];
        float4 T = decode_box(l, pr);
        for (int i = 0; i < nA; ++i) acc += giou_pair(ab[i], T);
    }
    for (int off = 32; off > 0; off >>= 1) acc += __shfl_down(acc, off);
    if (lane == 0) wsum[wid] = acc;
    __syncthreads();
    if (threadIdx.x == 0) {
        float t = 0.f;
        #pragma unroll
        for (int w = 0; w < TPB / 64; ++w) t += wsum[w];
        s_part[blk] = t;                     // unconditional
    }
}

// k3: finalize. Kernel boundary provides grid-wide visibility.
__global__ __launch_bounds__(TPB) void finalize_kernel(
    const int* __restrict__ cnt_a,
    const unsigned long long* __restrict__ masks,
    const float* __restrict__ s_part,
    int B, int wpb, int bpb, float* __restrict__ out) {
    int tid = threadIdx.x;
    __shared__ int   ntb[16], nab[16];
    __shared__ float sb[16];
    if (tid < 16) { ntb[tid] = 0; nab[tid] = 0; sb[tid] = 0.f; }
    __syncthreads();
    int nwave = B * wpb;                     // 256
    if (tid < nwave) {
        int bb = tid / wpb;
        int nt = __popcll(masks[tid]);
        int na = cnt_a[tid];
        if (nt) atomicAdd(&ntb[bb], nt);
        if (na) atomicAdd(&nab[bb], na);
    }
    int nblk = B * bpb;                      // 64
    if (tid < nblk) {
        int bb = tid / bpb;
        atomicAdd(&sb[bb], s_part[tid]);
    }
    __syncthreads();
    if (tid == 0) {
        float tsum = 0.f, nsum = 0.f;
        for (int bb = 0; bb < B; ++bb) {
            float ntf = (float)ntb[bb];
            bool bt = ntb[bb] > 0, ba = nab[bb] > 0;
            float term = (bt && ba) ? (ntf - sb[bb] / fmaxf(ntf, 1.f))
                                    : ((bt != ba) ? 1.f : 0.f);
            tsum += term;
            nsum += ntf;
        }
        out[0] = tsum / fmaxf(nsum, 1.f);
    }
}

extern "C" void kernel_launch(void* const* d_in, const int* in_sizes, int n_in,
                              void* d_out, int out_size, void* d_ws, size_t ws_size,
                              hipStream_t stream) {
    const float* conf   = (const float*)d_in[0];
    const float* loc    = (const float*)d_in[1];
    const int*   tconf  = (const int*)  d_in[2];
    const float* tloc   = (const float*)d_in[3];
    const float* priors = (const float*)d_in[4];
    float* out = (float*)d_out;

    int P = in_sizes[4] / 4;          // priors: [P,4]
    int B = in_sizes[2] / P;          // target_confidence: [B,P]
    int C = in_sizes[0] / (B * P);    // confidence: [B,P,C]
    int wpb  = P >> 6;                // wave slots per batch (32)
    int nwave = B * wpb;              // 256
    int bpb  = P / TPB;               // blocks per batch (8)
    int nblk = B * bpb;               // 64

    // ws: cnt_a[nwave] int | s_part[nblk] float | masks[nwave] u64 | regions
    // (all slots written unconditionally -> no zero-init, no memset dispatch)
    int*   cnt_a  = (int*)d_ws;
    float* s_part = (float*)(cnt_a + nwave);
    size_t off_m  = ((size_t)(nwave * 4 + nblk * 4) + 15) & ~(size_t)15;
    unsigned long long* masks = (unsigned long long*)((char*)d_ws + off_m);
    size_t off_r  = (off_m + (size_t)nwave * 8 + 15) & ~(size_t)15;
    float4* regions = (float4*)((char*)d_ws + off_r);

    mask_kernel<<<nblk, TPB, 0, stream>>>(conf, loc, tconf, priors,
                                          P, C, cnt_a, masks, regions);
    pair_kernel<<<nblk, TPB, 0, stream>>>(tloc, priors, regions,
                                          cnt_a, masks, s_part, P);
    finalize_kernel<<<1, TPB, 0, stream>>>(cnt_a, masks, s_part,
                                           B, wpb, bpb, out);
}